// Round 6
// baseline (273.399 us; speedup 1.0000x reference)
//
#include <hip/hip_runtime.h>
#include <hip/hip_bf16.h>

// GAT fused forward loss.
// e_ij = lrelu(s_i + d_j) is rank-1 => flash-style masked softmax aggregation
// with P built on the fly in bf16, P@Wh via MFMA 16x16x32.
// relu(elu(x)) == relu(x); no softmax max-shift needed (|s+d| < ~8).
// R6: k_pack v3 -- lane-CONTIGUOUS dwordx4 reads (1KB/instr, no 64B-stride
//     request inflation), shfl_xor nibble combine to the SAME u16 mask
//     layout as R5 (consumer k_attn unchanged), 2-deep pipeline, 64KB
//     sequential stream per wave, (256,8) occupancy.

#define NN 8192
#define FTDIM 512
#define CDIM 64
#define NTRAIN 1024
#define LOG2E 1.44269504088896f

typedef __attribute__((ext_vector_type(8))) short short8;
typedef __attribute__((ext_vector_type(4))) float f32x4;
typedef __attribute__((ext_vector_type(4))) int i32x4;

static __device__ __forceinline__ unsigned short f2bf(float x) {
    return __bfloat16_as_ushort(__float2bfloat16(x));
}

// ---------------------------------------------------------------------------
// Kernel A: Wh = feat @ W. Each wave computes 8 rows (one j-block), lane c
// owns column c. Writes Vt2[jblk][c][e] = bf16(Wh[jblk*8+e][c]) (contiguous
// 256B per 16-lane B-fragment group in k_attn). Stores factored-exp tables:
//   sQ[i] = (E1, E2, th) = (2^s', 2^(0.2 s'), 2^(-s'))
//   dE[j] = (e1, e2)     = (2^d', 2^(0.2 d'))     with s',d' = log2e-scaled.
// Then P = (e1d > th) ? E1*e1d : E2*e2d  ==  exp(lrelu(s+d)) exactly.
// ---------------------------------------------------------------------------
__global__ __launch_bounds__(256) void k_wh(
    const float* __restrict__ feat, const float* __restrict__ W,
    const float* __restrict__ av, unsigned short* __restrict__ Vt2,
    float4* __restrict__ sQ, float2* __restrict__ dE)
{
    const int lane = threadIdx.x & 63;
    const int wv   = (int)((blockIdx.x * blockDim.x + threadIdx.x) >> 6);
    const int row0 = wv * 8;
    const int c    = lane;

    float acc[8];
#pragma unroll
    for (int r = 0; r < 8; ++r) acc[r] = 0.f;

    for (int k = 0; k < FTDIM; k += 4) {
        f32x4 f[8];
#pragma unroll
        for (int r = 0; r < 8; ++r)
            f[r] = *(const f32x4*)(feat + (size_t)(row0 + r) * FTDIM + k);
#pragma unroll
        for (int kk = 0; kk < 4; ++kk) {
            float wval = W[(k + kk) * CDIM + c];
#pragma unroll
            for (int r = 0; r < 8; ++r)
                acc[r] = fmaf(f[r][kk], wval, acc[r]);
        }
    }

    short8 v;
#pragma unroll
    for (int r = 0; r < 8; ++r) v[r] = (short)f2bf(acc[r]);
    *(short8*)(Vt2 + (size_t)wv * 512 + c * 8) = v;   // [jblk][c][8]

    const float a1 = av[c], a2 = av[CDIM + c];
#pragma unroll
    for (int r = 0; r < 8; ++r) {
        float s_ = acc[r] * a1;
        float d_ = acc[r] * a2;
#pragma unroll
        for (int off = 32; off; off >>= 1) {
            s_ += __shfl_xor(s_, off);
            d_ += __shfl_xor(d_, off);
        }
        if (lane == 0) {
            const float sp = s_ * LOG2E, dp_ = d_ * LOG2E;
            sQ[row0 + r] = make_float4(__builtin_amdgcn_exp2f(sp),
                                       __builtin_amdgcn_exp2f(0.2f * sp),
                                       __builtin_amdgcn_exp2f(-sp), 0.f);
            dE[row0 + r] = make_float2(__builtin_amdgcn_exp2f(dp_),
                                       __builtin_amdgcn_exp2f(0.2f * dp_));
        }
    }
}

// ---------------------------------------------------------------------------
// Kernel P v3: bit-pack adjacency. 2048 blocks x 256 => 8192 waves; exactly
// 16 iters/wave, SEQUENTIAL (wave streams 64KB contiguously). Per iter:
// 4x dwordx4, each instruction lane-CONTIGUOUS (lane l reads ints base+4l ->
// 1KB/instr, minimal memory requests). Each lane packs a nibble; two
// shfl_xor combines give lanes l%4==0 the u16 for j-group l/4 -- IDENTICAL
// mask layout to R5: maskB[w] bit e == adj_flat[w*16+e].
// 2-deep software pipeline; ~52 VGPR -> 8 waves/SIMD.
// ---------------------------------------------------------------------------
__global__ __launch_bounds__(256, 8) void k_pack(
    const int* __restrict__ adj1, const int* __restrict__ adj2,
    unsigned short* __restrict__ maskB)
{
    const int lane = threadIdx.x & 63;
    const int wv = (int)((blockIdx.x * blockDim.x + threadIdx.x) >> 6);
    const long long NSQ = (long long)NN * NN;          // 2^26

    const int* __restrict__ src = (wv < 4096) ? adj1 : adj2;
    const long long lbase0 = ((long long)(wv & 4095)) << 14;  // *16 iters *1024 ints
    const long long gbase0 = ((long long)wv) << 14;           // global (concat layers)

    i32x4 A0, A1, A2, A3, B0, B1, B2, B3;

#define LOADP(T0, T1, T2, T3, U) do {                                          \
    const int* _p = src + lbase0 + ((long long)(U) << 10) + 4 * lane;          \
    T0 = *(const i32x4*)(_p);                                                  \
    T1 = *(const i32x4*)(_p + 256);                                            \
    T2 = *(const i32x4*)(_p + 512);                                            \
    T3 = *(const i32x4*)(_p + 768);                                            \
} while (0)

#define PROCP(T0, T1, T2, T3, U) do {                                          \
    const long long _w16 = ((gbase0 + ((long long)(U) << 10)) >> 4);           \
    i32x4 _vv[4] = {T0, T1, T2, T3};                                           \
    _Pragma("unroll")                                                          \
    for (int k = 0; k < 4; ++k) {                                              \
        i32x4 _v = _vv[k];                                                     \
        unsigned n = (_v[0] != 0 ? 1u : 0u) | (_v[1] != 0 ? 2u : 0u)           \
                   | (_v[2] != 0 ? 4u : 0u) | (_v[3] != 0 ? 8u : 0u);          \
        unsigned a = n | ((unsigned)__shfl_xor((int)n, 1) << 4);               \
        unsigned b = a | ((unsigned)__shfl_xor((int)a, 2) << 8);               \
        if ((lane & 3) == 0)                                                   \
            maskB[_w16 + k * 16 + (lane >> 2)] = (unsigned short)b;            \
    }                                                                          \
} while (0)

    LOADP(A0, A1, A2, A3, 0);
#pragma unroll 1
    for (int u = 0; u < 16; u += 2) {
        LOADP(B0, B1, B2, B3, u + 1);
        PROCP(A0, A1, A2, A3, u);
        if (u + 2 < 16) LOADP(A0, A1, A2, A3, u + 2);
        PROCP(B0, B1, B2, B3, u + 1);
    }
#undef LOADP
#undef PROCP
}

// ---------------------------------------------------------------------------
// Kernel B: fused masked-softmax aggregation on the bitmask (raw-adj
// fallback). Wave owns 16 rows x one j-chunk (SC=8 -> 8192 waves, 24/CU at
// (256,6)). Per 32-j tile, per lane: 1 mask word + 4 dE f32x4 + 4 Vt2 short8
// (9 independent loads, no barriers -> TLP hides L2 latency); P built with
// {cmp, cndmask x2, mul} per element (factored exp, no transcendental);
// 4 MFMAs for numP + 1 MFMA vs B=ones for Z (matrix pipe otherwise idle).
// Fragment layouts verified in R1.
// ---------------------------------------------------------------------------
template<bool USEMASK>
__global__ __launch_bounds__(256, 6) void k_attn(
    const int* __restrict__ adj1, const int* __restrict__ adj2,
    const unsigned* __restrict__ maskW,
    const unsigned short* __restrict__ Vt2, const float4* __restrict__ sQ,
    const float2* __restrict__ dE, float* __restrict__ numP,
    float* __restrict__ zP, const int scLog2)
{
    const int lane = threadIdx.x & 63;
    const int w = (int)((blockIdx.x * blockDim.x + threadIdx.x) >> 6);
    const int layer = w >> (9 + scLog2);
    const int rem = w & ((1 << (9 + scLog2)) - 1);
    const int rb = rem >> scLog2;
    const int sc = rem & ((1 << scLog2) - 1);

    const int r  = lane & 15;
    const int kg = lane >> 4;
    const int i  = rb * 16 + r;

    const int jchunk = NN >> scLog2;
    const int jbase  = sc * jchunk + kg * 8;
    const int niter  = jchunk >> 5;

    const int* __restrict__ adj = (layer == 0) ? adj1 : adj2;
    const int*            arow  = adj + (size_t)i * NN + jbase;
    const unsigned*       mrowp = maskW + (size_t)(layer * NN + i) * (NN >> 5)
                                        + sc * (jchunk >> 5);
    const f32x4*          dEp   = (const f32x4*)(dE + jbase);  // 4 f32x4 = lane's 8 (e1,e2)
    const unsigned short* vt2p  = Vt2 + (((size_t)jbase >> 3) << 9) + ((size_t)r << 3);

    const float4 sq = sQ[i];
    const float E1 = sq.x, E2 = sq.y, th = sq.z;

    // B = ones fragment for the Z row-sum MFMA (bf16 1.0 = 0x3F80)
    short8 bOnes;
#pragma unroll
    for (int e = 0; e < 8; ++e) bOnes[e] = (short)0x3F80;

    f32x4 acc0 = {0.f, 0.f, 0.f, 0.f};
    f32x4 acc1 = acc0, acc2 = acc0, acc3 = acc0, accz = acc0;

    for (int jt = 0; jt < niter; ++jt) {
        unsigned mw = 0;
        i32x4 m0, m1;
        if constexpr (USEMASK) {
            mw = mrowp[jt];
        } else {
            m0 = *(const i32x4*)(arow + jt * 32);
            m1 = *(const i32x4*)(arow + jt * 32 + 4);
        }
        const f32x4* dp = dEp + (size_t)jt * 8;
        f32x4 q0 = dp[0], q1 = dp[1], q2 = dp[2], q3 = dp[3];
        const unsigned short* vp = vt2p + (size_t)jt * 2048;
        short8 b0 = *(const short8*)(vp);
        short8 b1 = *(const short8*)(vp + 128);
        short8 b2 = *(const short8*)(vp + 256);
        short8 b3 = *(const short8*)(vp + 384);

        const unsigned ms = USEMASK ? (mw >> (kg * 8)) : 0u;
        short8 af;
#pragma unroll
        for (int e = 0; e < 8; ++e) {
            float e1, e2;
            switch (e >> 1) {
                case 0: e1 = q0[(e & 1) * 2]; e2 = q0[(e & 1) * 2 + 1]; break;
                case 1: e1 = q1[(e & 1) * 2]; e2 = q1[(e & 1) * 2 + 1]; break;
                case 2: e1 = q2[(e & 1) * 2]; e2 = q2[(e & 1) * 2 + 1]; break;
                default: e1 = q3[(e & 1) * 2]; e2 = q3[(e & 1) * 2 + 1]; break;
            }
            const bool pos = e1 > th;                 // <=> s'+d' > 0
            float p = (pos ? e1 : e2) * (pos ? E1 : E2);
            const bool on = USEMASK ? (((ms >> e) & 1u) != 0u)
                                    : ((e < 4 ? m0[e] : m1[e - 4]) != 0);
            p = on ? p : 0.f;
            af[e] = (short)f2bf(p);
        }

        acc0 = __builtin_amdgcn_mfma_f32_16x16x32_bf16(af, b0, acc0, 0, 0, 0);
        acc1 = __builtin_amdgcn_mfma_f32_16x16x32_bf16(af, b1, acc1, 0, 0, 0);
        acc2 = __builtin_amdgcn_mfma_f32_16x16x32_bf16(af, b2, acc2, 0, 0, 0);
        acc3 = __builtin_amdgcn_mfma_f32_16x16x32_bf16(af, b3, acc3, 0, 0, 0);
        accz = __builtin_amdgcn_mfma_f32_16x16x32_bf16(af, bOnes, accz, 0, 0, 0);
    }

    const size_t chunkbase = (size_t)((layer << scLog2) + sc) * NN;
    const int orow0 = rb * 16 + kg * 4;

    // accz[q] = Z of row (kg*4+q), identical across the 16 col-lanes.
    if (r == 0) {
#pragma unroll
        for (int q = 0; q < 4; ++q) zP[chunkbase + orow0 + q] = accz[q];
    }

#pragma unroll
    for (int q = 0; q < 4; ++q) {
        float* op = numP + (chunkbase + orow0 + q) * CDIM + r;
        op[0]  = acc0[q];
        op[16] = acc1[q];
        op[32] = acc2[q];
        op[48] = acc3[q];
    }
}

template __global__ void k_attn<true>(const int*, const int*, const unsigned*,
    const unsigned short*, const float4*, const float2*, float*, float*, const int);
template __global__ void k_attn<false>(const int*, const int*, const unsigned*,
    const unsigned short*, const float4*, const float2*, float*, float*, const int);

// ---------------------------------------------------------------------------
// Kernel C: per-training-sample loss. One wave per sample, lane = class.
// ---------------------------------------------------------------------------
__global__ __launch_bounds__(256) void k_loss(
    const float* __restrict__ numP, const float* __restrict__ zP,
    const int* __restrict__ labels, const int* __restrict__ idxt,
    float* __restrict__ losses, const int SC)
{
    const int lane = threadIdx.x & 63;
    const int k = (int)((blockIdx.x * blockDim.x + threadIdx.x) >> 6);
    const int i = idxt[k];

    float logit = 0.f;
#pragma unroll
    for (int l = 0; l < 2; ++l) {
        float nsum = 0.f, zsum = 0.f;
        for (int s = 0; s < SC; ++s) {
            size_t b = (size_t)(l * SC + s) * NN + i;
            nsum += numP[b * CDIM + lane];
            zsum += zP[b];
        }
        logit += fmaxf(nsum / zsum, 0.f);   // relu(elu(x)) == relu(x)
    }
    logit *= 0.5f;

    float m = logit;
#pragma unroll
    for (int off = 32; off; off >>= 1) m = fmaxf(m, __shfl_xor(m, off));
    float ex = __expf(logit - m);
    float sum = ex;
#pragma unroll
    for (int off = 32; off; off >>= 1) sum += __shfl_xor(sum, off);
    const float logp = logit - m - __logf(sum);

    const int y = labels[i];
    const float t = __shfl(logp, y);
    if (lane == 0) losses[k] = -t;
}

// ---------------------------------------------------------------------------
// Kernel D: mean of 1024 per-sample losses -> d_out[0].
// ---------------------------------------------------------------------------
__global__ __launch_bounds__(256) void k_reduce(
    const float* __restrict__ losses, float* __restrict__ out)
{
    __shared__ float sbuf[4];
    const int tid = threadIdx.x;
    float v = losses[tid] + losses[tid + 256] + losses[tid + 512] + losses[tid + 768];
#pragma unroll
    for (int off = 32; off; off >>= 1) v += __shfl_xor(v, off);
    if ((tid & 63) == 0) sbuf[tid >> 6] = v;
    __syncthreads();
    if (tid == 0) out[0] = (sbuf[0] + sbuf[1] + sbuf[2] + sbuf[3]) * (1.f / 1024.f);
}

// ---------------------------------------------------------------------------
extern "C" void kernel_launch(void* const* d_in, const int* in_sizes, int n_in,
                              void* d_out, int out_size, void* d_ws, size_t ws_size,
                              hipStream_t stream)
{
    const float* feat   = (const float*)d_in[0];
    const float* W      = (const float*)d_in[1];
    const float* av     = (const float*)d_in[2];
    const int*   adj1   = (const int*)d_in[3];
    const int*   adj2   = (const int*)d_in[4];
    const int*   labels = (const int*)d_in[5];
    const int*   idxt   = (const int*)d_in[6];

    const size_t MASKB = 2ull * NN * (NN / 32) * sizeof(unsigned);  // 16.78 MB
    const size_t HEAD  = (1u << 20) + (192u << 10);  // Vt2 1MB + sQ 128KB + dE 64KB

    auto needed = [&](size_t S, bool mask) -> size_t {
        return HEAD + (mask ? MASKB : 0)
             + 2 * S * NN * sizeof(float)
             + 2 * S * (size_t)NN * CDIM * sizeof(float)
             + NTRAIN * sizeof(float);
    };

    bool useMask = false;
    int scLog2 = 0;
    for (int s = 3; s >= 0; --s)
        if (ws_size >= needed((size_t)1 << s, true)) { useMask = true; scLog2 = s; break; }
    if (!useMask) {
        scLog2 = (ws_size >= needed(4, false)) ? 2
               : (ws_size >= needed(2, false)) ? 1 : 0;
    }
    const int SC = 1 << scLog2;

    char* ws = (char*)d_ws;
    unsigned short* Vt2 = (unsigned short*)ws;                 // 1 MB
    float4* sQ = (float4*)(ws + (1u << 20));                   // 128 KB
    float2* dEv = (float2*)(ws + (1u << 20) + (128u << 10));   // 64 KB
    char* p = ws + HEAD;
    unsigned* maskW = (unsigned*)p;
    if (useMask) p += MASKB;
    float* zP   = (float*)p;
    float* numP = (float*)(p + 2 * SC * NN * sizeof(float));
    float* losses = (float*)((char*)numP + 2 * (size_t)SC * NN * CDIM * sizeof(float));

    hipLaunchKernelGGL(k_wh, dim3(256), dim3(256), 0, stream,
                       feat, W, av, Vt2, sQ, dEv);
    if (useMask) {
        hipLaunchKernelGGL(k_pack, dim3(2048), dim3(256), 0, stream,
                           adj1, adj2, (unsigned short*)maskW);
        hipLaunchKernelGGL((k_attn<true>), dim3(256 * SC), dim3(256), 0, stream,
                           adj1, adj2, maskW, Vt2, sQ, dEv, numP, zP, scLog2);
    } else {
        hipLaunchKernelGGL((k_attn<false>), dim3(256 * SC), dim3(256), 0, stream,
                           adj1, adj2, maskW, Vt2, sQ, dEv, numP, zP, scLog2);
    }
    hipLaunchKernelGGL(k_loss, dim3(NTRAIN / 4), dim3(256), 0, stream,
                       numP, zP, labels, idxt, losses, SC);
    hipLaunchKernelGGL(k_reduce, dim3(1), dim3(256), 0, stream,
                       losses, (float*)d_out);
}